// Round 20
// baseline (171.503 us; speedup 1.0000x reference)
//
#include <hip/hip_runtime.h>
#include <hip/hip_bf16.h>

typedef __attribute__((ext_vector_type(8))) short short8;
typedef __attribute__((ext_vector_type(4))) float floatx4;

#define IMGH 112
#define IMGW 112
#define SHIFT 3
#define NWIN 49

#define XSTR 144     // s_a row stride (x -> V^T -> O share this 18432B buffer)
#define QKSTR 264    // s_qk row stride (Q 0-127 -> P after qf pre-read; K 128-255)
#define VTSTR 72     // V^T [128][72] overlaid on s_a (64*144 == 128*72)

#define LOG2E 1.4426950408889634f
#define QSCALE (0.17677669529663687f * LOG2E)
#define NMASK (-100.0f * LOG2E)

__device__ inline unsigned short f2bf1(float f) {
    unsigned r;
    asm("v_cvt_pk_bf16_f32 %0, %1, %1" : "=v"(r) : "v"(f));
    return (unsigned short)r;
}
__device__ inline unsigned cvtpk(float lo, float hi) {
    unsigned r;
    asm("v_cvt_pk_bf16_f32 %0, %1, %2" : "=v"(r) : "v"(lo), "v"(hi));
    return r;
}
__device__ inline float bf2f(short s) {
    return __uint_as_float(((unsigned)(unsigned short)s) << 16);
}

__device__ inline floatx4 mfma16(short8 a, short8 b, floatx4 c) {
    return __builtin_amdgcn_mfma_f32_16x16x32_bf16(a, b, c, 0, 0, 0);
}
__device__ inline floatx4 zero4() {
    floatx4 z; z[0] = 0.f; z[1] = 0.f; z[2] = 0.f; z[3] = 0.f; return z;
}
__device__ inline short8 ones8() {
    short8 z;
    #pragma unroll
    for (int i = 0; i < 8; ++i) z[i] = (short)0x3F80;
    return z;
}

// weight fp32 -> bf16 (Q rows pre-scaled by scale*log2e)
__global__ __launch_bounds__(256) void convert_w(const float* __restrict__ qkv_w,
                                                 const float* __restrict__ proj_w,
                                                 short* __restrict__ ws) {
    int i = blockIdx.x * 256 + threadIdx.x;
    if (i < 49152) {
        float v = qkv_w[i];
        if (i < 16384) v *= QSCALE;          // rows 0..127 = Q features
        ws[i] = (short)f2bf1(v);
    }
    if (i < 16384) ws[49152 + i] = (short)f2bf1(proj_w[i]);
}

// One block per 7x7 window, 8 waves, 54096B LDS -> 3 blocks/CU (24 waves).
// Buffer roles: s_a = x -> V^T -> O; s_qk = Q,K -> (P in dead Q cols), K.
__global__ __launch_bounds__(512, 6) void win_attn_mfma8d(
    const float* __restrict__ x,
    const float* __restrict__ qkv_b,
    const float* __restrict__ proj_b,
    const float* __restrict__ rpb,
    const short* __restrict__ wq,    // bf16 qkv_w [384][128] (Q rows scaled)
    const short* __restrict__ wp,    // bf16 proj_w [128][128]
    float* __restrict__ out)
{
    __shared__ alignas(16) short s_a [64 * XSTR];    // 18432 B
    __shared__ alignas(16) short s_qk[64 * QKSTR];   // 33792 B
    __shared__ short s_rpbh[4 * 170];                // 1360 B (bf16, *LOG2E)
    __shared__ int s_meta[64];                       // t13 | reg<<8
    __shared__ int s_gout[64];                       // scatter pixel index

    short* s_vt = s_a;                               // V^T [128][VTSTR] overlay

    const int tid = threadIdx.x;
    const int w    = tid >> 6;         // wave 0..7
    const int l    = tid & 63;
    const int l15  = l & 15;
    const int lg   = l >> 4;           // 0..3
    const int hgrp = w >> 2;           // head pair 0/1
    const int m_w  = w & 3;            // query row tile
    const int swz  = (l15 & 3) << 4;

    const int blk = blockIdx.x;
    const int b   = blk >> 8;
    const int wi  = blk & 255;
    const int hs0 = (wi >> 4) * 7;
    const int ws0 = (wi & 15) * 7;

    const float* xb = x + (size_t)b * (IMGH * IMGW * 128);

    // ---- stage 0: metadata + rpb(bf16) + x -> LDS ----
    if (tid < 64) {
        int rowc = tid < NWIN ? tid : NWIN - 1;
        int ri = (rowc * 9363) >> 16;
        int ci = rowc - ri * 7;
        int hc = hs0 + ri, wc = ws0 + ci;
        int reg = (hc < 105 ? 0 : (hc < 109 ? 1 : 2)) * 3
                + (wc < 105 ? 0 : (wc < 109 ? 1 : 2));
        if (tid >= NWIN) reg = 255;
        s_meta[tid] = (ri * 13 + ci) | (reg << 8);
        int gh = hc + SHIFT; if (gh >= IMGH) gh -= IMGH;
        int gw = wc + SHIFT; if (gw >= IMGW) gw -= IMGW;
        s_gout[tid] = gh * IMGW + gw;
    }
    for (int idx = tid; idx < 676; idx += 512) {      // rpb[d][h] -> s_rpbh[h][d]
        s_rpbh[(idx & 3) * 170 + (idx >> 2)] = (short)f2bf1(rpb[idx] * LOG2E);
    }
    {
        int row  = tid >> 3;           // 0..63
        int col0 = (tid & 7) << 4;     // 0,16,...,112
        int cs   = col0 ^ ((row & 3) << 4);
        uint4 u0 = {0,0,0,0}, u1 = {0,0,0,0};
        if (row < NWIN) {
            int rr = (row * 9363) >> 16;
            int cc = row - rr * 7;
            int gh = hs0 + rr + SHIFT; if (gh >= IMGH) gh -= IMGH;
            int gw = ws0 + cc + SHIFT; if (gw >= IMGW) gw -= IMGW;
            const float* px = xb + (((size_t)(gh * IMGW + gw)) << 7) + col0;
            float4 a = *(const float4*)(px + 0);
            float4 c4 = *(const float4*)(px + 4);
            float4 e = *(const float4*)(px + 8);
            float4 g = *(const float4*)(px + 12);
            u0.x = cvtpk(a.x, a.y);   u0.y = cvtpk(a.z, a.w);
            u0.z = cvtpk(c4.x, c4.y); u0.w = cvtpk(c4.z, c4.w);
            u1.x = cvtpk(e.x, e.y);   u1.y = cvtpk(e.z, e.w);
            u1.z = cvtpk(g.x, g.y);   u1.w = cvtpk(g.z, g.w);
        }
        *(uint4*)&s_a[row * XSTR + cs]     = u0;
        *(uint4*)&s_a[row * XSTR + cs + 8] = u1;
    }
    __syncthreads();   // #1

    // ---- stage 1: V tile (w) into regs + 2 Q/K tiles (2w, 2w+1) into s_qk ----
    uint2 vreg[4];
    {
        const int j0v = 256 + (w << 4);
        const short* wbv = wq + ((j0v + l15) << 7) + lg * 8;
        short8 bfrv[4];
        #pragma unroll
        for (int kk = 0; kk < 4; ++kk) bfrv[kk] = *(const short8*)(wbv + kk * 32);
        const float bv = qkv_b[j0v + l15];

        const int j00 = w << 5;
        const short* wb0 = wq + ((j00 + l15) << 7) + lg * 8;
        short8 bfr0[4];
        #pragma unroll
        for (int kk = 0; kk < 4; ++kk) bfr0[kk] = *(const short8*)(wb0 + kk * 32);
        float4 b40 = *(const float4*)(qkv_b + j00 + lg * 4);
        if (j00 < 128) { b40.x *= QSCALE; b40.y *= QSCALE; b40.z *= QSCALE; b40.w *= QSCALE; }

        #pragma unroll
        for (int m = 0; m < 4; ++m) {
            short8 af[4];
            #pragma unroll
            for (int kk = 0; kk < 4; ++kk)
                af[kk] = *(const short8*)&s_a[(m * 16 + l15) * XSTR + ((kk * 32 + lg * 8) ^ swz)];
            floatx4 av = zero4(), a0 = zero4();
            #pragma unroll
            for (int kk = 0; kk < 4; ++kk) {
                av = mfma16(af[kk], bfrv[kk], av);   // D[tok][feat] for V
                a0 = mfma16(bfr0[kk], af[kk], a0);   // D[feat][tok] for Q/K
            }
            vreg[m].x = cvtpk(av[0] + bv, av[1] + bv);
            vreg[m].y = cvtpk(av[2] + bv, av[3] + bv);
            uint2 u;
            u.x = cvtpk(a0[0] + b40.x, a0[1] + b40.y);
            u.y = cvtpk(a0[2] + b40.z, a0[3] + b40.w);
            *(uint2*)&s_qk[(m * 16 + l15) * QKSTR + ((j00 + lg * 4) ^ swz)] = u;
        }

        const int j01 = j00 + 16;
        const short* wb1 = wq + ((j01 + l15) << 7) + lg * 8;
        short8 bfr1[4];
        #pragma unroll
        for (int kk = 0; kk < 4; ++kk) bfr1[kk] = *(const short8*)(wb1 + kk * 32);
        float4 b41 = *(const float4*)(qkv_b + j01 + lg * 4);
        if (j01 < 128) { b41.x *= QSCALE; b41.y *= QSCALE; b41.z *= QSCALE; b41.w *= QSCALE; }
        #pragma unroll
        for (int m = 0; m < 4; ++m) {
            short8 af[4];
            #pragma unroll
            for (int kk = 0; kk < 4; ++kk)
                af[kk] = *(const short8*)&s_a[(m * 16 + l15) * XSTR + ((kk * 32 + lg * 8) ^ swz)];
            floatx4 a1 = zero4();
            #pragma unroll
            for (int kk = 0; kk < 4; ++kk) a1 = mfma16(bfr1[kk], af[kk], a1);
            uint2 u;
            u.x = cvtpk(a1[0] + b41.x, a1[1] + b41.y);
            u.y = cvtpk(a1[2] + b41.z, a1[3] + b41.w);
            *(uint2*)&s_qk[(m * 16 + l15) * QKSTR + ((j01 + lg * 4) ^ swz)] = u;
        }
    }
    __syncthreads();   // #2: all x reads done -> s_a free; Q/K visible

    // ---- V^T write (wave-private rows) + qf pre-read for BOTH heads ----
    #pragma unroll
    for (int m = 0; m < 4; ++m)
        *(uint2*)&s_vt[(w * 16 + l15) * VTSTR + ((m * 16 + lg * 4) ^ swz)] = vreg[m];
    short8 qf0 = *(const short8*)&s_qk[(m_w * 16 + l15) * QKSTR + (((hgrp * 2 + 0) * 32 + lg * 8) ^ swz)];
    short8 qf1 = *(const short8*)&s_qk[(m_w * 16 + l15) * QKSTR + (((hgrp * 2 + 1) * 32 + lg * 8) ^ swz)];
    __syncthreads();   // #3: V^T visible to all waves

    // ---- stage 2: per head: QK^T, exp2(+bias), P->dead Q cols, PV ----
    floatx4 accO[2][2];
    float   inv2[2];
    const short8 vone = ones8();
    #pragma unroll
    for (int hh = 0; hh < 2; ++hh) {
        const int h = hgrp * 2 + hh;
        short8 qf = hh ? qf1 : qf0;
        floatx4 accS[4];
        #pragma unroll
        for (int n = 0; n < 4; ++n) {
            short8 kf = *(const short8*)&s_qk[(n * 16 + l15) * QKSTR + (128 + ((h * 32 + lg * 8) ^ swz))];
            accS[n] = mfma16(kf, qf, zero4());   // D[key][query=l15]
        }
        // lazy bias+mask (s_meta/s_rpbh stable) + exp2; P -> Q-region cols hgrp*64+
        {
            int mi = s_meta[m_w * 16 + l15];
            int ti = mi & 255, gi = mi >> 8;
            const short* rh = s_rpbh + h * 170;
            #pragma unroll
            for (int n = 0; n < 4; ++n) {
                int4 mk = *(const int4*)&s_meta[n * 16 + lg * 4];
                float pv[4];
                #pragma unroll
                for (int c = 0; c < 4; ++c) {
                    int mv = (&mk.x)[c];
                    int d = ti - (mv & 255) + 84;
                    float bias = bf2f(rh[d]) + ((gi == (mv >> 8)) ? 0.f : NMASK);
                    pv[c] = exp2f(accS[n][c] + bias);
                }
                uint2 u;
                u.x = cvtpk(pv[0], pv[1]);
                u.y = cvtpk(pv[2], pv[3]);
                *(uint2*)&s_qk[(m_w * 16 + l15) * QKSTR + hgrp * 64 + ((n * 16 + lg * 4) ^ swz)] = u;
            }
        }
        short8 pa[2];
        #pragma unroll
        for (int kt = 0; kt < 2; ++kt)
            pa[kt] = *(const short8*)&s_qk[(m_w * 16 + l15) * QKSTR + hgrp * 64 + ((kt * 32 + lg * 8) ^ swz)];
        floatx4 accSum = zero4();
        #pragma unroll
        for (int vt = 0; vt < 2; ++vt) accO[hh][vt] = zero4();
        #pragma unroll
        for (int kt = 0; kt < 2; ++kt) {
            #pragma unroll
            for (int vt = 0; vt < 2; ++vt) {
                short8 vf = *(const short8*)&s_vt[(h * 32 + vt * 16 + l15) * VTSTR + ((kt * 32 + lg * 8) ^ swz)];
                accO[hh][vt] = mfma16(vf, pa[kt], accO[hh][vt]);   // D[feat][query]
            }
            accSum = mfma16(vone, pa[kt], accSum);
        }
        inv2[hh] = 1.f / accSum[0];
    }
    __syncthreads();   // #4: all PV reads of V^T done -> s_a free for O

    // ---- O (normalized, packed) -> s_a ----
    #pragma unroll
    for (int hh = 0; hh < 2; ++hh)
        #pragma unroll
        for (int vt = 0; vt < 2; ++vt) {
            uint2 u;
            u.x = cvtpk(accO[hh][vt][0] * inv2[hh], accO[hh][vt][1] * inv2[hh]);
            u.y = cvtpk(accO[hh][vt][2] * inv2[hh], accO[hh][vt][3] * inv2[hh]);
            *(uint2*)&s_a[(m_w * 16 + l15) * XSTR + ((hgrp * 64 + hh * 32 + vt * 16 + lg * 4) ^ swz)] = u;
        }
    __syncthreads();   // #5: O complete

    // ---- stage 3: swapped proj (D[outfeat][token]) + dwordx4 scatter ----
    {
        floatx4 acc[4];
        #pragma unroll
        for (int m = 0; m < 4; ++m) acc[m] = zero4();
        const short* wbp = wp + ((w * 16 + l15) << 7) + lg * 8;
        #pragma unroll
        for (int kk = 0; kk < 4; ++kk) {
            short8 pw = *(const short8*)(wbp + kk * 32);
            #pragma unroll
            for (int m = 0; m < 4; ++m) {
                short8 of = *(const short8*)&s_a[(m * 16 + l15) * XSTR + ((kk * 32 + lg * 8) ^ swz)];
                acc[m] = mfma16(pw, of, acc[m]);
            }
        }
        float4 pb = *(const float4*)(proj_b + w * 16 + lg * 4);
        const size_t obase = (size_t)b * (IMGH * IMGW);
        #pragma unroll
        for (int m = 0; m < 4; ++m) {
            int token = m * 16 + l15;
            if (token < NWIN) {
                float4 o4;
                o4.x = acc[m][0] + pb.x;
                o4.y = acc[m][1] + pb.y;
                o4.z = acc[m][2] + pb.z;
                o4.w = acc[m][3] + pb.w;
                *(float4*)&out[((obase + s_gout[token]) << 7) + (w << 4) + lg * 4] = o4;
            }
        }
    }
}

extern "C" void kernel_launch(void* const* d_in, const int* in_sizes, int n_in,
                              void* d_out, int out_size, void* d_ws, size_t ws_size,
                              hipStream_t stream) {
    const float* x      = (const float*)d_in[0];
    const float* qkv_w  = (const float*)d_in[1];
    const float* qkv_b  = (const float*)d_in[2];
    const float* proj_w = (const float*)d_in[3];
    const float* proj_b = (const float*)d_in[4];
    const float* rpb    = (const float*)d_in[5];
    float* out = (float*)d_out;
    short* wbf = (short*)d_ws;   // [0,49152) qkv_w bf16 (Q rows pre-scaled), [49152,65536) proj_w

    hipLaunchKernelGGL(convert_w, dim3(192), dim3(256), 0, stream, qkv_w, proj_w, wbf);
    hipLaunchKernelGGL(win_attn_mfma8d, dim3(4096), dim3(512), 0, stream,
                       x, qkv_b, proj_b, rpb, wbf, wbf + 49152, out);
}

// Round 21
// 127.543 us; speedup vs baseline: 1.3447x; 1.3447x over previous
//
#include <hip/hip_runtime.h>
#include <hip/hip_bf16.h>

typedef __attribute__((ext_vector_type(8))) short short8;
typedef __attribute__((ext_vector_type(4))) float floatx4;

#define IMGH 112
#define IMGW 112
#define SHIFT 3
#define NWIN 49

#define XSTR 144     // s_a row stride (x -> V^T -> O share this 18432B buffer)
#define QKSTR 264    // s_qk row stride (Q 0-127 -> P after qf pre-read; K 128-255)
#define VTSTR 72     // V^T [128][72] overlaid on s_a (64*144 == 128*72)

#define LOG2E 1.4426950408889634f
#define QSCALE (0.17677669529663687f * LOG2E)
#define NMASK (-100.0f * LOG2E)

__device__ inline unsigned short f2bf1(float f) {
    unsigned r;
    asm("v_cvt_pk_bf16_f32 %0, %1, %1" : "=v"(r) : "v"(f));
    return (unsigned short)r;
}
__device__ inline unsigned cvtpk(float lo, float hi) {
    unsigned r;
    asm("v_cvt_pk_bf16_f32 %0, %1, %2" : "=v"(r) : "v"(lo), "v"(hi));
    return r;
}
__device__ inline float bf2f(short s) {
    return __uint_as_float(((unsigned)(unsigned short)s) << 16);
}

__device__ inline floatx4 mfma16(short8 a, short8 b, floatx4 c) {
    return __builtin_amdgcn_mfma_f32_16x16x32_bf16(a, b, c, 0, 0, 0);
}
__device__ inline floatx4 zero4() {
    floatx4 z; z[0] = 0.f; z[1] = 0.f; z[2] = 0.f; z[3] = 0.f; return z;
}
__device__ inline short8 ones8() {
    short8 z;
    #pragma unroll
    for (int i = 0; i < 8; ++i) z[i] = (short)0x3F80;
    return z;
}

// weight fp32 -> bf16 (Q rows pre-scaled by scale*log2e)
__global__ __launch_bounds__(256) void convert_w(const float* __restrict__ qkv_w,
                                                 const float* __restrict__ proj_w,
                                                 short* __restrict__ ws) {
    int i = blockIdx.x * 256 + threadIdx.x;
    if (i < 49152) {
        float v = qkv_w[i];
        if (i < 16384) v *= QSCALE;          // rows 0..127 = Q features
        ws[i] = (short)f2bf1(v);
    }
    if (i < 16384) ws[49152 + i] = (short)f2bf1(proj_w[i]);
}

// One block per 7x7 window, 8 waves, 54272B LDS -> 3 blocks/CU IF VGPR<=85.
// launch_bounds(512,4): no artificial register pressure (r20's (512,6)
// collapsed the allocator to 40 VGPR + scratch spill). Stage 1 split into
// three passes to lower peak pressure below 85.
__global__ __launch_bounds__(512, 4) void win_attn_mfma8d(
    const float* __restrict__ x,
    const float* __restrict__ qkv_b,
    const float* __restrict__ proj_b,
    const float* __restrict__ rpb,
    const short* __restrict__ wq,    // bf16 qkv_w [384][128] (Q rows scaled)
    const short* __restrict__ wp,    // bf16 proj_w [128][128]
    float* __restrict__ out)
{
    __shared__ alignas(16) short s_a [64 * XSTR];    // 18432 B
    __shared__ alignas(16) short s_qk[64 * QKSTR];   // 33792 B
    __shared__ short s_rpbh[4 * 170];                // 1360 B (bf16, *LOG2E)
    __shared__ int s_meta[64];                       // t13 | reg<<8
    __shared__ int s_gout[64];                       // scatter pixel index

    short* s_vt = s_a;                               // V^T [128][VTSTR] overlay

    const int tid = threadIdx.x;
    const int w    = tid >> 6;         // wave 0..7
    const int l    = tid & 63;
    const int l15  = l & 15;
    const int lg   = l >> 4;           // 0..3
    const int hgrp = w >> 2;           // head pair 0/1
    const int m_w  = w & 3;            // query row tile
    const int swz  = (l15 & 3) << 4;

    const int blk = blockIdx.x;
    const int b   = blk >> 8;
    const int wi  = blk & 255;
    const int hs0 = (wi >> 4) * 7;
    const int ws0 = (wi & 15) * 7;

    const float* xb = x + (size_t)b * (IMGH * IMGW * 128);

    // ---- stage 0: metadata + rpb(bf16) + x -> LDS ----
    if (tid < 64) {
        int rowc = tid < NWIN ? tid : NWIN - 1;
        int ri = (rowc * 9363) >> 16;
        int ci = rowc - ri * 7;
        int hc = hs0 + ri, wc = ws0 + ci;
        int reg = (hc < 105 ? 0 : (hc < 109 ? 1 : 2)) * 3
                + (wc < 105 ? 0 : (wc < 109 ? 1 : 2));
        if (tid >= NWIN) reg = 255;
        s_meta[tid] = (ri * 13 + ci) | (reg << 8);
        int gh = hc + SHIFT; if (gh >= IMGH) gh -= IMGH;
        int gw = wc + SHIFT; if (gw >= IMGW) gw -= IMGW;
        s_gout[tid] = gh * IMGW + gw;
    }
    for (int idx = tid; idx < 676; idx += 512) {      // rpb[d][h] -> s_rpbh[h][d]
        s_rpbh[(idx & 3) * 170 + (idx >> 2)] = (short)f2bf1(rpb[idx] * LOG2E);
    }
    {
        int row  = tid >> 3;           // 0..63
        int col0 = (tid & 7) << 4;     // 0,16,...,112
        int cs   = col0 ^ ((row & 3) << 4);
        uint4 u0 = {0,0,0,0}, u1 = {0,0,0,0};
        if (row < NWIN) {
            int rr = (row * 9363) >> 16;
            int cc = row - rr * 7;
            int gh = hs0 + rr + SHIFT; if (gh >= IMGH) gh -= IMGH;
            int gw = ws0 + cc + SHIFT; if (gw >= IMGW) gw -= IMGW;
            const float* px = xb + (((size_t)(gh * IMGW + gw)) << 7) + col0;
            float4 a = *(const float4*)(px + 0);
            float4 c4 = *(const float4*)(px + 4);
            float4 e = *(const float4*)(px + 8);
            float4 g = *(const float4*)(px + 12);
            u0.x = cvtpk(a.x, a.y);   u0.y = cvtpk(a.z, a.w);
            u0.z = cvtpk(c4.x, c4.y); u0.w = cvtpk(c4.z, c4.w);
            u1.x = cvtpk(e.x, e.y);   u1.y = cvtpk(e.z, e.w);
            u1.z = cvtpk(g.x, g.y);   u1.w = cvtpk(g.z, g.w);
        }
        *(uint4*)&s_a[row * XSTR + cs]     = u0;
        *(uint4*)&s_a[row * XSTR + cs + 8] = u1;
    }
    __syncthreads();   // #1

    // ---- stage 1 (3 low-pressure passes): V tile -> regs; Q/K tiles -> s_qk ----
    uint2 vreg[4];
    {
        // pass A: V tile (n-tile 16+w), D[tok][feat]
        const int j0v = 256 + (w << 4);
        const short* wbv = wq + ((j0v + l15) << 7) + lg * 8;
        short8 bfrv[4];
        #pragma unroll
        for (int kk = 0; kk < 4; ++kk) bfrv[kk] = *(const short8*)(wbv + kk * 32);
        const float bv = qkv_b[j0v + l15];
        #pragma unroll
        for (int m = 0; m < 4; ++m) {
            short8 af[4];
            #pragma unroll
            for (int kk = 0; kk < 4; ++kk)
                af[kk] = *(const short8*)&s_a[(m * 16 + l15) * XSTR + ((kk * 32 + lg * 8) ^ swz)];
            floatx4 av = zero4();
            #pragma unroll
            for (int kk = 0; kk < 4; ++kk) av = mfma16(af[kk], bfrv[kk], av);
            vreg[m].x = cvtpk(av[0] + bv, av[1] + bv);
            vreg[m].y = cvtpk(av[2] + bv, av[3] + bv);
        }
    }
    #pragma unroll
    for (int t = 0; t < 2; ++t) {
        // pass B/C: Q or K tile (n-tile 2w+t), swapped D[feat][tok]
        const int j0 = (w << 5) + (t << 4);
        const short* wb = wq + ((j0 + l15) << 7) + lg * 8;
        short8 bfr[4];
        #pragma unroll
        for (int kk = 0; kk < 4; ++kk) bfr[kk] = *(const short8*)(wb + kk * 32);
        float4 b4 = *(const float4*)(qkv_b + j0 + lg * 4);
        if (j0 < 128) { b4.x *= QSCALE; b4.y *= QSCALE; b4.z *= QSCALE; b4.w *= QSCALE; }
        #pragma unroll
        for (int m = 0; m < 4; ++m) {
            short8 af[4];
            #pragma unroll
            for (int kk = 0; kk < 4; ++kk)
                af[kk] = *(const short8*)&s_a[(m * 16 + l15) * XSTR + ((kk * 32 + lg * 8) ^ swz)];
            floatx4 a0 = zero4();
            #pragma unroll
            for (int kk = 0; kk < 4; ++kk) a0 = mfma16(bfr[kk], af[kk], a0);
            uint2 u;
            u.x = cvtpk(a0[0] + b4.x, a0[1] + b4.y);
            u.y = cvtpk(a0[2] + b4.z, a0[3] + b4.w);
            *(uint2*)&s_qk[(m * 16 + l15) * QKSTR + ((j0 + lg * 4) ^ swz)] = u;
        }
    }
    __syncthreads();   // #2: all x reads done -> s_a free; Q/K visible

    // ---- V^T write (wave-private rows) + qf pre-read for BOTH heads ----
    #pragma unroll
    for (int m = 0; m < 4; ++m)
        *(uint2*)&s_vt[(w * 16 + l15) * VTSTR + ((m * 16 + lg * 4) ^ swz)] = vreg[m];
    short8 qf0 = *(const short8*)&s_qk[(m_w * 16 + l15) * QKSTR + (((hgrp * 2 + 0) * 32 + lg * 8) ^ swz)];
    short8 qf1 = *(const short8*)&s_qk[(m_w * 16 + l15) * QKSTR + (((hgrp * 2 + 1) * 32 + lg * 8) ^ swz)];
    __syncthreads();   // #3: V^T visible to all waves

    // ---- stage 2: per head: QK^T, exp2(+bias), P->dead Q cols, PV ----
    floatx4 accO[2][2];
    float   inv2[2];
    const short8 vone = ones8();
    #pragma unroll
    for (int hh = 0; hh < 2; ++hh) {
        const int h = hgrp * 2 + hh;
        short8 qf = hh ? qf1 : qf0;
        floatx4 accS[4];
        #pragma unroll
        for (int n = 0; n < 4; ++n) {
            short8 kf = *(const short8*)&s_qk[(n * 16 + l15) * QKSTR + (128 + ((h * 32 + lg * 8) ^ swz))];
            accS[n] = mfma16(kf, qf, zero4());   // D[key][query=l15]
        }
        // lazy bias+mask (s_meta/s_rpbh stable) + exp2; P -> Q-region cols hgrp*64+
        {
            int mi = s_meta[m_w * 16 + l15];
            int ti = mi & 255, gi = mi >> 8;
            const short* rh = s_rpbh + h * 170;
            #pragma unroll
            for (int n = 0; n < 4; ++n) {
                int4 mk = *(const int4*)&s_meta[n * 16 + lg * 4];
                float pv[4];
                #pragma unroll
                for (int c = 0; c < 4; ++c) {
                    int mv = (&mk.x)[c];
                    int d = ti - (mv & 255) + 84;
                    float bias = bf2f(rh[d]) + ((gi == (mv >> 8)) ? 0.f : NMASK);
                    pv[c] = exp2f(accS[n][c] + bias);
                }
                uint2 u;
                u.x = cvtpk(pv[0], pv[1]);
                u.y = cvtpk(pv[2], pv[3]);
                *(uint2*)&s_qk[(m_w * 16 + l15) * QKSTR + hgrp * 64 + ((n * 16 + lg * 4) ^ swz)] = u;
            }
        }
        short8 pa[2];
        #pragma unroll
        for (int kt = 0; kt < 2; ++kt)
            pa[kt] = *(const short8*)&s_qk[(m_w * 16 + l15) * QKSTR + hgrp * 64 + ((kt * 32 + lg * 8) ^ swz)];
        floatx4 accSum = zero4();
        #pragma unroll
        for (int vt = 0; vt < 2; ++vt) accO[hh][vt] = zero4();
        #pragma unroll
        for (int kt = 0; kt < 2; ++kt) {
            #pragma unroll
            for (int vt = 0; vt < 2; ++vt) {
                short8 vf = *(const short8*)&s_vt[(h * 32 + vt * 16 + l15) * VTSTR + ((kt * 32 + lg * 8) ^ swz)];
                accO[hh][vt] = mfma16(vf, pa[kt], accO[hh][vt]);   // D[feat][query]
            }
            accSum = mfma16(vone, pa[kt], accSum);
        }
        inv2[hh] = 1.f / accSum[0];
    }
    __syncthreads();   // #4: all PV reads of V^T done -> s_a free for O

    // ---- O (normalized, packed) -> s_a ----
    #pragma unroll
    for (int hh = 0; hh < 2; ++hh)
        #pragma unroll
        for (int vt = 0; vt < 2; ++vt) {
            uint2 u;
            u.x = cvtpk(accO[hh][vt][0] * inv2[hh], accO[hh][vt][1] * inv2[hh]);
            u.y = cvtpk(accO[hh][vt][2] * inv2[hh], accO[hh][vt][3] * inv2[hh]);
            *(uint2*)&s_a[(m_w * 16 + l15) * XSTR + ((hgrp * 64 + hh * 32 + vt * 16 + lg * 4) ^ swz)] = u;
        }
    __syncthreads();   // #5: O complete

    // ---- stage 3: swapped proj (D[outfeat][token]) + dwordx4 scatter ----
    {
        floatx4 acc[4];
        #pragma unroll
        for (int m = 0; m < 4; ++m) acc[m] = zero4();
        const short* wbp = wp + ((w * 16 + l15) << 7) + lg * 8;
        #pragma unroll
        for (int kk = 0; kk < 4; ++kk) {
            short8 pw = *(const short8*)(wbp + kk * 32);
            #pragma unroll
            for (int m = 0; m < 4; ++m) {
                short8 of = *(const short8*)&s_a[(m * 16 + l15) * XSTR + ((kk * 32 + lg * 8) ^ swz)];
                acc[m] = mfma16(pw, of, acc[m]);
            }
        }
        float4 pb = *(const float4*)(proj_b + w * 16 + lg * 4);
        const size_t obase = (size_t)b * (IMGH * IMGW);
        #pragma unroll
        for (int m = 0; m < 4; ++m) {
            int token = m * 16 + l15;
            if (token < NWIN) {
                float4 o4;
                o4.x = acc[m][0] + pb.x;
                o4.y = acc[m][1] + pb.y;
                o4.z = acc[m][2] + pb.z;
                o4.w = acc[m][3] + pb.w;
                *(float4*)&out[((obase + s_gout[token]) << 7) + (w << 4) + lg * 4] = o4;
            }
        }
    }
}

extern "C" void kernel_launch(void* const* d_in, const int* in_sizes, int n_in,
                              void* d_out, int out_size, void* d_ws, size_t ws_size,
                              hipStream_t stream) {
    const float* x      = (const float*)d_in[0];
    const float* qkv_w  = (const float*)d_in[1];
    const float* qkv_b  = (const float*)d_in[2];
    const float* proj_w = (const float*)d_in[3];
    const float* proj_b = (const float*)d_in[4];
    const float* rpb    = (const float*)d_in[5];
    float* out = (float*)d_out;
    short* wbf = (short*)d_ws;   // [0,49152) qkv_w bf16 (Q rows pre-scaled), [49152,65536) proj_w

    hipLaunchKernelGGL(convert_w, dim3(192), dim3(256), 0, stream, qkv_w, proj_w, wbf);
    hipLaunchKernelGGL(win_attn_mfma8d, dim3(4096), dim3(512), 0, stream,
                       x, qkv_b, proj_b, rpb, wbf, wbf + 49152, out);
}